// Round 2
// baseline (35.775 us; speedup 1.0000x reference)
//
#include <hip/hip_runtime.h>

// Problem constants (B, L, D from reference)
#define BB 64
#define LL 4096
#define DD 256
#define PP 64              // partial chunks per batch; rows per chunk = LL/PP = 64
#define ROWS_PER_CHUNK (LL / PP)
#define D4 (DD / 4)        // float4 elements per row = 64

// ---------------- Phase 1: per-(batch, chunk) partial sums ----------------
// One wave (64 threads) per block. lane owns float4 column `lane`.
// Wave reads one contiguous 1 KiB row per iteration (fully coalesced, 16 B/lane).
__global__ __launch_bounds__(64) void avg_partial_kernel(
    const float* __restrict__ in,        // [B, L, D]
    const int* __restrict__ len,         // [B]  (int32 — harness delivers JAX int as i32)
    float* __restrict__ ws)              // [B, PP, D]
{
    const int b    = blockIdx.x / PP;
    const int p    = blockIdx.x % PP;
    const int lane = threadIdx.x;        // 0..63

    const int lb   = len[b];
    const int row0 = p * ROWS_PER_CHUNK;
    int rend = row0 + ROWS_PER_CHUNK;
    if (rend > lb) rend = (lb > row0) ? lb : row0;

    float4 acc = make_float4(0.f, 0.f, 0.f, 0.f);
    const float4* __restrict__ base =
        (const float4*)(in + (size_t)b * LL * DD);

    for (int r = row0; r < rend; ++r) {
        float4 v = base[(size_t)r * D4 + lane];
        acc.x += v.x; acc.y += v.y; acc.z += v.z; acc.w += v.w;
    }

    // Always write (poisoned ws must be overwritten, even for fully-masked chunks)
    float4* __restrict__ wsb = (float4*)ws + ((size_t)b * PP + p) * D4;
    wsb[lane] = acc;
}

// ---------------- Phase 2: reduce partials, divide by length ----------------
__global__ __launch_bounds__(64) void avg_reduce_kernel(
    const float* __restrict__ ws,        // [B, PP, D]
    const int* __restrict__ len,         // [B]
    float* __restrict__ out)             // [B, D]
{
    const int b    = blockIdx.x;
    const int lane = threadIdx.x;        // 0..63

    float4 acc = make_float4(0.f, 0.f, 0.f, 0.f);
    const float4* __restrict__ wsb = (const float4*)ws + (size_t)b * PP * D4;

    #pragma unroll 4
    for (int p = 0; p < PP; ++p) {
        float4 v = wsb[(size_t)p * D4 + lane];
        acc.x += v.x; acc.y += v.y; acc.z += v.z; acc.w += v.w;
    }

    int lb = len[b];
    if (lb < 1) lb = 1;                  // reference guarantees len >= 1; belt-and-braces
    const float inv = 1.0f / (float)lb;
    float4 o = make_float4(acc.x * inv, acc.y * inv, acc.z * inv, acc.w * inv);
    ((float4*)out)[(size_t)b * D4 + lane] = o;
}

// ---------------- Fallback (tiny ws): zero-out + atomic accumulate ----------------
__global__ void avg_zero_out_kernel(float* __restrict__ out) {
    int i = blockIdx.x * blockDim.x + threadIdx.x;
    if (i < BB * DD) out[i] = 0.f;
}

__global__ __launch_bounds__(64) void avg_atomic_kernel(
    const float* __restrict__ in,
    const int* __restrict__ len,
    float* __restrict__ out)
{
    const int b    = blockIdx.x / PP;
    const int p    = blockIdx.x % PP;
    const int lane = threadIdx.x;

    int lb = len[b];
    if (lb < 1) lb = 1;
    const int row0 = p * ROWS_PER_CHUNK;
    int rend = row0 + ROWS_PER_CHUNK;
    if (rend > lb) rend = (lb > row0) ? lb : row0;
    if (rend <= row0) return;

    float4 acc = make_float4(0.f, 0.f, 0.f, 0.f);
    const float4* __restrict__ base = (const float4*)(in + (size_t)b * LL * DD);
    for (int r = row0; r < rend; ++r) {
        float4 v = base[(size_t)r * D4 + lane];
        acc.x += v.x; acc.y += v.y; acc.z += v.z; acc.w += v.w;
    }
    const float inv = 1.0f / (float)lb;
    float* o = out + (size_t)b * DD + lane * 4;
    atomicAdd(o + 0, acc.x * inv);
    atomicAdd(o + 1, acc.y * inv);
    atomicAdd(o + 2, acc.z * inv);
    atomicAdd(o + 3, acc.w * inv);
}

extern "C" void kernel_launch(void* const* d_in, const int* in_sizes, int n_in,
                              void* d_out, int out_size, void* d_ws, size_t ws_size,
                              hipStream_t stream) {
    const float* in  = (const float*)d_in[0];
    const int*   len = (const int*)d_in[1];
    float*       out = (float*)d_out;

    const size_t ws_needed = (size_t)BB * PP * DD * sizeof(float); // 4 MiB

    if (ws_size >= ws_needed && d_ws != nullptr) {
        float* ws = (float*)d_ws;
        avg_partial_kernel<<<BB * PP, 64, 0, stream>>>(in, len, ws);
        avg_reduce_kernel<<<BB, 64, 0, stream>>>(ws, len, out);
    } else {
        avg_zero_out_kernel<<<(BB * DD + 255) / 256, 256, 0, stream>>>(out);
        avg_atomic_kernel<<<BB * PP, 64, 0, stream>>>(in, len, out);
    }
}

// Round 3
// 33.794 us; speedup vs baseline: 1.0586x; 1.0586x over previous
//
#include <hip/hip_runtime.h>

// Problem constants (B, L, D from reference)
#define BB 64
#define LL 4096
#define DD 256
#define PP 64              // partial chunks per batch; rows per chunk = LL/PP = 64
#define ROWS_PER_CHUNK (LL / PP)
#define D4 (DD / 4)        // float4 elements per row = 64
#define WAVES 4            // waves per block in both kernels

// ---------------- Phase 1: per-(batch, chunk) partial sums ----------------
// 256-thread blocks = 4 waves; wave w owns chunk (blockIdx.x*4 + w).
// All 4 chunks of a block belong to the same batch (16 blocks per batch).
// Lane owns one float4 column slice -> each wave reads contiguous 1 KiB rows.
// Only ACTIVE chunks (p < ceil(len/64)) are computed/written; phase 2 reads
// only those, so inactive ws entries may stay poisoned harmlessly.
__global__ __launch_bounds__(256) void avg_partial_kernel(
    const float* __restrict__ in,        // [B, L, D]
    const int* __restrict__ len,         // [B] (int32)
    float* __restrict__ ws)              // [B, PP, D]
{
    const int w    = threadIdx.x >> 6;   // wave 0..3
    const int lane = threadIdx.x & 63;   // 0..63
    const int c    = blockIdx.x * WAVES + w;   // global chunk id
    const int b    = c >> 6;             // c / PP
    const int p    = c & 63;             // c % PP

    const int lb      = len[b];
    const int nchunks = (lb + ROWS_PER_CHUNK - 1) >> 6;   // ceil(lb/64), >= 1
    if (p >= nchunks) return;

    const int row0 = p * ROWS_PER_CHUNK;
    int rend = row0 + ROWS_PER_CHUNK;
    if (rend > lb) rend = lb;

    float4 acc = make_float4(0.f, 0.f, 0.f, 0.f);
    const float4* __restrict__ base = (const float4*)(in + (size_t)b * LL * DD);

    #pragma unroll 8
    for (int r = row0; r < rend; ++r) {
        float4 v = base[(size_t)r * D4 + lane];
        acc.x += v.x; acc.y += v.y; acc.z += v.z; acc.w += v.w;
    }

    float4* __restrict__ wsb = (float4*)ws + ((size_t)b * PP + p) * D4;
    wsb[lane] = acc;
}

// ---------------- Phase 2: reduce active partials, divide by length ----------------
// 64 blocks x 256 threads (4 waves). Wave w sums partials p = w, w+4, ...
// (only p < nchunks), then a 3-way LDS combine; wave 0 writes out.
__global__ __launch_bounds__(256) void avg_reduce_kernel(
    const float* __restrict__ ws,        // [B, PP, D]
    const int* __restrict__ len,         // [B]
    float* __restrict__ out)             // [B, D]
{
    const int b    = blockIdx.x;
    const int w    = threadIdx.x >> 6;
    const int lane = threadIdx.x & 63;

    int lb = len[b];
    if (lb < 1) lb = 1;
    const int nchunks = (lb + ROWS_PER_CHUNK - 1) >> 6;

    float4 acc = make_float4(0.f, 0.f, 0.f, 0.f);
    const float4* __restrict__ wsb = (const float4*)ws + (size_t)b * PP * D4;

    for (int p = w; p < nchunks; p += WAVES) {
        float4 v = wsb[(size_t)p * D4 + lane];
        acc.x += v.x; acc.y += v.y; acc.z += v.z; acc.w += v.w;
    }

    __shared__ float4 sh[WAVES - 1][64];
    if (w > 0) sh[w - 1][lane] = acc;
    __syncthreads();

    if (w == 0) {
        #pragma unroll
        for (int i = 0; i < WAVES - 1; ++i) {
            float4 v = sh[i][lane];
            acc.x += v.x; acc.y += v.y; acc.z += v.z; acc.w += v.w;
        }
        const float inv = 1.0f / (float)lb;
        float4 o = make_float4(acc.x * inv, acc.y * inv, acc.z * inv, acc.w * inv);
        ((float4*)out)[(size_t)b * D4 + lane] = o;
    }
}

// ---------------- Fallback (tiny ws): zero-out + atomic accumulate ----------------
__global__ void avg_zero_out_kernel(float* __restrict__ out) {
    int i = blockIdx.x * blockDim.x + threadIdx.x;
    if (i < BB * DD) out[i] = 0.f;
}

__global__ __launch_bounds__(64) void avg_atomic_kernel(
    const float* __restrict__ in,
    const int* __restrict__ len,
    float* __restrict__ out)
{
    const int b    = blockIdx.x / PP;
    const int p    = blockIdx.x % PP;
    const int lane = threadIdx.x;

    int lb = len[b];
    if (lb < 1) lb = 1;
    const int row0 = p * ROWS_PER_CHUNK;
    int rend = row0 + ROWS_PER_CHUNK;
    if (rend > lb) rend = (lb > row0) ? lb : row0;
    if (rend <= row0) return;

    float4 acc = make_float4(0.f, 0.f, 0.f, 0.f);
    const float4* __restrict__ base = (const float4*)(in + (size_t)b * LL * DD);
    for (int r = row0; r < rend; ++r) {
        float4 v = base[(size_t)r * D4 + lane];
        acc.x += v.x; acc.y += v.y; acc.z += v.z; acc.w += v.w;
    }
    const float inv = 1.0f / (float)lb;
    float* o = out + (size_t)b * DD + lane * 4;
    atomicAdd(o + 0, acc.x * inv);
    atomicAdd(o + 1, acc.y * inv);
    atomicAdd(o + 2, acc.z * inv);
    atomicAdd(o + 3, acc.w * inv);
}

extern "C" void kernel_launch(void* const* d_in, const int* in_sizes, int n_in,
                              void* d_out, int out_size, void* d_ws, size_t ws_size,
                              hipStream_t stream) {
    const float* in  = (const float*)d_in[0];
    const int*   len = (const int*)d_in[1];
    float*       out = (float*)d_out;

    const size_t ws_needed = (size_t)BB * PP * DD * sizeof(float); // 4 MiB

    if (ws_size >= ws_needed && d_ws != nullptr) {
        float* ws = (float*)d_ws;
        avg_partial_kernel<<<(BB * PP) / WAVES, 256, 0, stream>>>(in, len, ws);
        avg_reduce_kernel<<<BB, 256, 0, stream>>>(ws, len, out);
    } else {
        avg_zero_out_kernel<<<(BB * DD + 255) / 256, 256, 0, stream>>>(out);
        avg_atomic_kernel<<<BB * PP, 64, 0, stream>>>(in, len, out);
    }
}